// Round 2
// 182.810 us; speedup vs baseline: 1.0765x; 1.0765x over previous
//
#include <hip/hip_runtime.h>

// Problem constants (fixed by setup_inputs)
constexpr int B  = 16;
constexpr int N  = 4096;
constexpr int NP = 1024;
constexpr int C  = 64;
constexpr int NS = 32;            // nsample
constexpr int OC = C + 3;         // output channels = 67
constexpr float R2 = 0.2f * 0.2f; // radius^2

typedef float v4f __attribute__((ext_vector_type(4)));
typedef int   v4i __attribute__((ext_vector_type(4)));

// popcount of mask bits strictly below this lane (v_mbcnt pair)
__device__ __forceinline__ int mbcnt64(unsigned long long m) {
    return (int)__builtin_amdgcn_mbcnt_hi(
        (unsigned)(m >> 32),
        __builtin_amdgcn_mbcnt_lo((unsigned)m, 0u));
}

// Kernel 1: ball query, one WAVE per center, 256 points per iteration
// (4 consecutive points per lane => 3x global_load_dwordx4, fully coalesced).
// 2-deep software pipeline: next tile's loads issue before current tile's
// ballot chain. Hits are accumulated in a per-wave LDS buffer (ds_write_b128,
// off the vmcnt path); the epilogue does one coalesced 4x128B store.
// Semantics match the reference exactly: first NS points in index order with
// d2 < R2; unfilled slots replicate the first hit (index 0 if none).
__global__ __launch_bounds__(256)
void ball_query_kernel(const float* __restrict__ xyz,
                       const float* __restrict__ new_xyz,
                       float* __restrict__ out,
                       int* __restrict__ ws_idx)
{
    __shared__ __align__(16) float s_hits[4][NS][4]; // per-wave {idx,dx,dy,dz}

    const int wv   = threadIdx.x >> 6;
    const int wid  = (blockIdx.x << 2) + wv;   // center id (wave-uniform)
    const int lane = threadIdx.x & 63;
    const int b = wid >> 10;        // wid / NP
    const int p = wid & (NP - 1);   // wid % NP

    const float qx = new_xyz[wid * 3 + 0];  // wave-uniform
    const float qy = new_xyz[wid * 3 + 1];
    const float qz = new_xyz[wid * 3 + 2];

    const float* xb = xyz + (size_t)b * N * 3;
    const v4f* src = (const v4f*)xb;        // batch base is 16B-aligned
    const int l3 = lane * 3;

    float (*hits)[4] = s_hits[wv];

    // tile 0 preload: lane holds points 4*lane .. 4*lane+3 (48B contiguous)
    v4f A  = src[l3 + 0];
    v4f Bv = src[l3 + 1];
    v4f Cv = src[l3 + 2];

    int cnt = 0;
    int tile = 0;
    for (;;) {
        // ---- prefetch next tile (issues before the ballot chain) ----
        v4f nA, nB, nC;
        const bool more = (tile + 1) < (N / 256);
        if (more) {
            const v4f* s2 = src + (tile + 1) * 192 + l3;
            nA = s2[0]; nB = s2[1]; nC = s2[2];
        }

        // ---- distances for the 4 points (match numpy f32, no FMA fuse) ----
        const float dx0 = A.x  - qx, dy0 = A.y  - qy, dz0 = A.z  - qz;
        const float dx1 = A.w  - qx, dy1 = Bv.x - qy, dz1 = Bv.y - qz;
        const float dx2 = Bv.z - qx, dy2 = Bv.w - qy, dz2 = Cv.x - qz;
        const float dx3 = Cv.y - qx, dy3 = Cv.z - qy, dz3 = Cv.w - qz;
        const float d20 = __fadd_rn(__fadd_rn(__fmul_rn(dx0,dx0),__fmul_rn(dy0,dy0)),__fmul_rn(dz0,dz0));
        const float d21 = __fadd_rn(__fadd_rn(__fmul_rn(dx1,dx1),__fmul_rn(dy1,dy1)),__fmul_rn(dz1,dz1));
        const float d22 = __fadd_rn(__fadd_rn(__fmul_rn(dx2,dx2),__fmul_rn(dy2,dy2)),__fmul_rn(dz2,dz2));
        const float d23 = __fadd_rn(__fadd_rn(__fmul_rn(dx3,dx3),__fmul_rn(dy3,dy3)),__fmul_rn(dz3,dz3));
        const bool in0 = d20 < R2;
        const bool in1 = d21 < R2;
        const bool in2 = d22 < R2;
        const bool in3 = d23 < R2;
        const unsigned long long m0 = __ballot(in0);
        const unsigned long long m1 = __ballot(in1);
        const unsigned long long m2 = __ballot(in2);
        const unsigned long long m3 = __ballot(in3);

        // lane-major index order: ALL 4 points of earlier lanes precede ours.
        const int T = mbcnt64(m0) + mbcnt64(m1) + mbcnt64(m2) + mbcnt64(m3);
        const int jb = tile * 256 + lane * 4;

        int sl = cnt + T;
        if (in0) { if (sl < NS) { v4f h; h.x = __int_as_float(jb + 0); h.y = dx0; h.z = dy0; h.w = dz0; *(v4f*)hits[sl] = h; } ++sl; }
        if (in1) { if (sl < NS) { v4f h; h.x = __int_as_float(jb + 1); h.y = dx1; h.z = dy1; h.w = dz1; *(v4f*)hits[sl] = h; } ++sl; }
        if (in2) { if (sl < NS) { v4f h; h.x = __int_as_float(jb + 2); h.y = dx2; h.z = dy2; h.w = dz2; *(v4f*)hits[sl] = h; } ++sl; }
        if (in3) { if (sl < NS) { v4f h; h.x = __int_as_float(jb + 3); h.y = dx3; h.z = dy3; h.w = dz3; *(v4f*)hits[sl] = h; } ++sl; }

        cnt += (int)(__popcll(m0) + __popcll(m1) + __popcll(m2) + __popcll(m3));
        if (cnt >= NS || !more) break;
        A = nA; Bv = nB; Cv = nC; ++tile;
    }

    // ---- epilogue: coalesced 4x128B stores from lanes 0..31 ----
    float* out_x = out + (((size_t)b * OC + 0) * NP + p) * NS;
    float* out_y = out + (((size_t)b * OC + 1) * NP + p) * NS;
    float* out_z = out + (((size_t)b * OC + 2) * NP + p) * NS;
    int*   idx_p = ws_idx + (size_t)wid * NS;

    const int cntc = cnt < NS ? cnt : NS;
    if (lane < NS) {
        v4f h;
        if (cnt > 0) {
            // unfilled slots replicate the first hit (LDS slot 0)
            h = *(const v4f*)hits[lane < cntc ? lane : 0];
        } else {
            // no point in radius: reference uses index 0
            h.x = __int_as_float(0);
            h.y = xb[0] - qx;
            h.z = xb[1] - qy;
            h.w = xb[2] - qz;
        }
        idx_p[lane] = __float_as_int(h.x);
        out_x[lane] = h.y;
        out_y[lane] = h.z;
        out_z[lane] = h.w;
    }
}

// Kernel 2 (unchanged, near its ~25us write-BW floor): one block per
// (b, pair-of-channels): stage two contiguous 16 KB points rows in LDS
// (one 32 KB contiguous copy), then each int4 idx load feeds two float4
// streaming stores.
__global__ __launch_bounds__(256)
void group_points_kernel(const float* __restrict__ points,
                         const int* __restrict__ ws_idx,
                         float* __restrict__ out)
{
    __shared__ float s_row[2 * N]; // 32 KB

    const int bc = blockIdx.x;           // over B * (C/2) = 512
    const int b  = bc >> 5;
    const int c2 = (bc & 31) * 2;        // first of the two channels

    // rows c2 and c2+1 are contiguous in memory: one 8192-float copy
    const v4f* row4 = (const v4f*)(points + ((size_t)b * C + c2) * N);
    v4f* s4 = (v4f*)s_row;
    #pragma unroll
    for (int i = threadIdx.x; i < 2 * N / 4; i += 256)
        s4[i] = row4[i];
    __syncthreads();

    const v4i* idx4 = (const v4i*)(ws_idx + (size_t)b * NP * NS);
    v4f* out0 = (v4f*)(out + ((size_t)b * OC + 3 + c2) * NP * NS);
    v4f* out1 = (v4f*)(out + ((size_t)b * OC + 4 + c2) * NP * NS);

    for (int t = threadIdx.x; t < NP * NS / 4; t += 256) {
        const v4i id = idx4[t];
        v4f va, vb;
        va.x = s_row[id.x];
        va.y = s_row[id.y];
        va.z = s_row[id.z];
        va.w = s_row[id.w];
        vb.x = s_row[N + id.x];
        vb.y = s_row[N + id.y];
        vb.z = s_row[N + id.z];
        vb.w = s_row[N + id.w];
        __builtin_nontemporal_store(va, &out0[t]);
        __builtin_nontemporal_store(vb, &out1[t]);
    }
}

extern "C" void kernel_launch(void* const* d_in, const int* in_sizes, int n_in,
                              void* d_out, int out_size, void* d_ws, size_t ws_size,
                              hipStream_t stream)
{
    const float* xyz     = (const float*)d_in[0]; // (B, N, 3)
    const float* new_xyz = (const float*)d_in[1]; // (B, NP, 3)
    const float* points  = (const float*)d_in[2]; // (B, C, N)
    float* out = (float*)d_out;                   // (B, 67, NP, NS)
    int* ws_idx = (int*)d_ws;                     // B*NP*NS ints = 2 MB

    // one wave per center, 4 waves per block
    ball_query_kernel<<<(B * NP) / 4, 256, 0, stream>>>(xyz, new_xyz, out, ws_idx);

    // one block per (b, channel-pair)
    group_points_kernel<<<B * (C / 2), 256, 0, stream>>>(points, ws_idx, out);
}